// Round 5
// baseline (191.035 us; speedup 1.0000x reference)
//
#include <hip/hip_runtime.h>

#define N_SEL 8192
#define SUB_SZ 32
#define N_SUB 256
#define N_GRAPH 64
#define N_FULL 12288
#define E_RAW 262144
#define N_PERS 4
#define D 128
#define EPSILON 0.1f
#define LAMB1 0.5f

// ---- bucketed fill+merge geometry ----
#define CHUNK_FLOATS 16384                   // 64 KB chunk per block
#define N_CHUNKS 9216                        // 12288*12288 / 16384
#define CAP 256                              // bucket capacity (expected max ~120)
#define WS_NEEDED ((size_t)N_CHUNKS * 4 + (size_t)N_CHUNKS * CAP * 8)

typedef float f4_t __attribute__((ext_vector_type(4)));

__global__ __launch_bounds__(256) void zero_counts_kernel(int* __restrict__ counts)
{
    int i = blockIdx.x * 256 + threadIdx.x;
    if (i < N_CHUNKS) counts[i] = 0;
}

__device__ __forceinline__ void bucket_append(
        int* counts, uint2* entries, long long flat, float v)
{
    int chunk = (int)(flat >> 14);           // /CHUNK_FLOATS
    int local = (int)(flat & (CHUNK_FLOATS - 1));
    int slot = atomicAdd(&counts[chunk], 1);
    if (slot < CAP)
        entries[(size_t)chunk * CAP + slot] = make_uint2((unsigned)local, __float_as_uint(v));
}

// Blocks [0,256): cosine subgraph blocks -> bucket entries.
// Blocks [256,1280): raw edges -> bucket entries (+0.5 each).
__global__ __launch_bounds__(256) void build_kernel(
        const float* __restrict__ x,
        const float* __restrict__ Wc,
        const float* __restrict__ sscore,
        const int*   __restrict__ smap,
        const int*   __restrict__ rei,
        int*   __restrict__ counts,
        uint2* __restrict__ entries)
{
    const int tid = threadIdx.x;

    if (blockIdx.x >= N_SUB) {
        int e = (blockIdx.x - N_SUB) * 256 + tid;
        long long r = rei[e];
        long long c = rei[E_RAW + e];
        bucket_append(counts, entries, r * (long long)N_FULL + c, 1.0f - LAMB1);
        return;
    }

    const int s    = blockIdx.x;
    const int base = s * SUB_SZ;

    __shared__ float xs[SUB_SZ][D + 1];
    __shared__ float w2[N_PERS][D];
    __shared__ float rnorm[N_PERS][SUB_SZ];
    __shared__ int   map_s[SUB_SZ];
    __shared__ float rowscore;

    for (int k = tid; k < SUB_SZ * D; k += 256) {
        int i = k >> 7;
        int d = k & (D - 1);
        xs[i][d] = x[(base + i) * D + d];
    }
    for (int k = tid; k < N_PERS * D; k += 256) {
        float w = Wc[k];
        ((float*)w2)[k] = w * w;
    }
    if (tid < SUB_SZ) map_s[tid] = smap[base + tid];
    if (tid == 0) {
        int g4 = (s >> 2) << 2;
        float sum = sscore[g4] + sscore[g4 + 1] + sscore[g4 + 2] + sscore[g4 + 3];
        rowscore = (sscore[s] / sum) * LAMB1;
    }
    __syncthreads();

    if (tid < N_PERS * SUB_SZ) {
        int p = tid >> 5;
        int i = tid & 31;
        float acc = 0.f;
        #pragma unroll 8
        for (int d = 0; d < D; ++d) {
            float v = xs[i][d];
            acc = fmaf(v * v, w2[p][d], acc);
        }
        rnorm[p][i] = 1.0f / fmaxf(sqrtf(acc), 1e-12f);
    }
    __syncthreads();

    for (int e = tid; e < SUB_SZ * SUB_SZ; e += 256) {
        int i = e >> 5;
        int j = e & 31;
        if (i == j) continue;
        float a0 = 0.f, a1 = 0.f, a2 = 0.f, a3 = 0.f;
        #pragma unroll 8
        for (int d = 0; d < D; ++d) {
            float prod = xs[i][d] * xs[j][d];
            a0 = fmaf(prod, w2[0][d], a0);
            a1 = fmaf(prod, w2[1][d], a1);
            a2 = fmaf(prod, w2[2][d], a2);
            a3 = fmaf(prod, w2[3][d], a3);
        }
        float adj = 0.25f * (a0 * rnorm[0][i] * rnorm[0][j] +
                             a1 * rnorm[1][i] * rnorm[1][j] +
                             a2 * rnorm[2][i] * rnorm[2][j] +
                             a3 * rnorm[3][i] * rnorm[3][j]);
        if (adj > EPSILON) {
            long long row = map_s[i];
            long long col = map_s[j];
            bucket_append(counts, entries, row * (long long)N_FULL + col, adj * rowscore);
        }
    }
}

// One block per 64 KB chunk: zero it with REGULAR stores (lines stay in this
// XCD's L2), drain via __syncthreads (emits vmcnt(0)), then apply the bucketed
// entries as global atomicAdds -> L2-hit RMWs, no second HBM pass, no LDS.
__global__ __launch_bounds__(256) void fill_merge_kernel(
        const int*   __restrict__ counts,
        const uint2* __restrict__ entries,
        float* __restrict__ out)
{
    const int chunk = blockIdx.x;
    const int tid   = threadIdx.x;

    f4_t* out4 = (f4_t*)out + (size_t)chunk * (CHUNK_FLOATS / 4);
    const f4_t z = (f4_t){0.f, 0.f, 0.f, 0.f};
    #pragma unroll
    for (int k = 0; k < CHUNK_FLOATS / 4 / 256; ++k)
        out4[tid + k * 256] = z;

    __syncthreads();   // compiler emits s_waitcnt vmcnt(0) before s_barrier

    int cnt = counts[chunk];
    if (cnt > CAP) cnt = CAP;
    float* base = out + (size_t)chunk * CHUNK_FLOATS;
    for (int e = tid; e < cnt; e += 256) {
        uint2 en = entries[(size_t)chunk * CAP + e];
        atomicAdd(&base[en.x], __uint_as_float(en.y));
    }
}

// ---------------- fallback path (R3): zero fill + atomic scatter ----------------
#define N4_TOTAL 37748736
#define FILL_BLOCKS 4096
#define PER_BLOCK (N4_TOTAL / FILL_BLOCKS)
#define FILL_ITERS (PER_BLOCK / 256)

__global__ __launch_bounds__(256) void zero_kernel(f4_t* __restrict__ out)
{
    size_t base = (size_t)blockIdx.x * PER_BLOCK + threadIdx.x;
    const f4_t z = (f4_t){0.f, 0.f, 0.f, 0.f};
    #pragma unroll
    for (int k = 0; k < FILL_ITERS; ++k)
        __builtin_nontemporal_store(z, &out[base + (size_t)k * 256]);
}

__global__ __launch_bounds__(256) void scatter_kernel(
        const float* __restrict__ x,
        const float* __restrict__ Wc,
        const float* __restrict__ sscore,
        const int*   __restrict__ smap,
        const int*   __restrict__ rei,
        float* __restrict__ out)
{
    const int tid = threadIdx.x;

    if (blockIdx.x >= N_SUB) {
        int e = (blockIdx.x - N_SUB) * 256 + tid;
        long long r = rei[e];
        long long c = rei[E_RAW + e];
        atomicAdd(&out[r * (long long)N_FULL + c], 1.0f - LAMB1);
        return;
    }

    const int s    = blockIdx.x;
    const int base = s * SUB_SZ;

    __shared__ float xs[SUB_SZ][D + 1];
    __shared__ float w2[N_PERS][D];
    __shared__ float rnorm[N_PERS][SUB_SZ];
    __shared__ int   map_s[SUB_SZ];
    __shared__ float rowscore;

    for (int k = tid; k < SUB_SZ * D; k += 256) {
        int i = k >> 7;
        int d = k & (D - 1);
        xs[i][d] = x[(base + i) * D + d];
    }
    for (int k = tid; k < N_PERS * D; k += 256) {
        float w = Wc[k];
        ((float*)w2)[k] = w * w;
    }
    if (tid < SUB_SZ) map_s[tid] = smap[base + tid];
    if (tid == 0) {
        int g4 = (s >> 2) << 2;
        float sum = sscore[g4] + sscore[g4 + 1] + sscore[g4 + 2] + sscore[g4 + 3];
        rowscore = (sscore[s] / sum) * LAMB1;
    }
    __syncthreads();

    if (tid < N_PERS * SUB_SZ) {
        int p = tid >> 5;
        int i = tid & 31;
        float acc = 0.f;
        #pragma unroll 8
        for (int d = 0; d < D; ++d) {
            float v = xs[i][d];
            acc = fmaf(v * v, w2[p][d], acc);
        }
        rnorm[p][i] = 1.0f / fmaxf(sqrtf(acc), 1e-12f);
    }
    __syncthreads();

    for (int e = tid; e < SUB_SZ * SUB_SZ; e += 256) {
        int i = e >> 5;
        int j = e & 31;
        if (i == j) continue;
        float a0 = 0.f, a1 = 0.f, a2 = 0.f, a3 = 0.f;
        #pragma unroll 8
        for (int d = 0; d < D; ++d) {
            float prod = xs[i][d] * xs[j][d];
            a0 = fmaf(prod, w2[0][d], a0);
            a1 = fmaf(prod, w2[1][d], a1);
            a2 = fmaf(prod, w2[2][d], a2);
            a3 = fmaf(prod, w2[3][d], a3);
        }
        float adj = 0.25f * (a0 * rnorm[0][i] * rnorm[0][j] +
                             a1 * rnorm[1][i] * rnorm[1][j] +
                             a2 * rnorm[2][i] * rnorm[2][j] +
                             a3 * rnorm[3][i] * rnorm[3][j]);
        if (adj > EPSILON) {
            long long row = map_s[i];
            long long col = map_s[j];
            atomicAdd(&out[row * (long long)N_FULL + col], adj * rowscore);
        }
    }
}

extern "C" void kernel_launch(void* const* d_in, const int* in_sizes, int n_in,
                              void* d_out, int out_size, void* d_ws, size_t ws_size,
                              hipStream_t stream) {
    const float* x      = (const float*)d_in[0];
    const float* Wc     = (const float*)d_in[1];
    const float* sscore = (const float*)d_in[2];
    const int* smap = (const int*)d_in[4];
    const int* rei  = (const int*)d_in[7];
    float* out = (float*)d_out;

    if (ws_size >= WS_NEEDED) {
        int*   counts  = (int*)d_ws;
        uint2* entries = (uint2*)((char*)d_ws + (size_t)N_CHUNKS * 4);

        zero_counts_kernel<<<(N_CHUNKS + 255) / 256, 256, 0, stream>>>(counts);
        build_kernel<<<N_SUB + E_RAW / 256, 256, 0, stream>>>(
            x, Wc, sscore, smap, rei, counts, entries);
        fill_merge_kernel<<<N_CHUNKS, 256, 0, stream>>>(counts, entries, out);
    } else {
        zero_kernel<<<FILL_BLOCKS, 256, 0, stream>>>((f4_t*)out);
        scatter_kernel<<<N_SUB + E_RAW / 256, 256, 0, stream>>>(
            x, Wc, sscore, smap, rei, out);
    }
}

// Round 6
// 160.403 us; speedup vs baseline: 1.1910x; 1.1910x over previous
//
#include <hip/hip_runtime.h>

#define N_SEL 8192
#define SUB_SZ 32
#define N_SUB 256
#define N_GRAPH 64
#define N_FULL 12288
#define E_RAW 262144
#define N_PERS 4
#define D 128
#define EPSILON 0.1f
#define LAMB1 0.5f

#define CAP_E 96                 // raw-edge bin capacity per row (lambda~21)
#define OVF_CAP 8192             // overflow list capacity (expected use: 0)

typedef float f4_t __attribute__((ext_vector_type(4)));

// ---- workspace layout ----
// counts   : N_FULL ints
// inv_map  : N_FULL ints
// attr_vals: N_SEL*SUB_SZ floats (1 MB)
// raw_cols : N_FULL*CAP_E ints (4.7 MB)
// ovf_cnt  : 1 int (padded to 16)
// ovf      : OVF_CAP uint2 (row,col)
#define OFF_COUNTS   0
#define OFF_INVMAP   ((size_t)N_FULL * 4)
#define OFF_ATTR     (OFF_INVMAP + (size_t)N_FULL * 4)
#define OFF_RAWCOLS  (OFF_ATTR + (size_t)N_SEL * SUB_SZ * 4)
#define OFF_OVFCNT   (OFF_RAWCOLS + (size_t)N_FULL * CAP_E * 4)
#define OFF_OVF      (OFF_OVFCNT + 16)
#define WS_NEEDED    (OFF_OVF + (size_t)OVF_CAP * 8)

__global__ __launch_bounds__(256) void prep_kernel(int* __restrict__ counts,
                                                   int* __restrict__ inv_map,
                                                   int* __restrict__ ovf_cnt)
{
    int t = blockIdx.x * 256 + threadIdx.x;
    if (t < N_FULL) { counts[t] = 0; inv_map[t] = -1; }
    if (t == 0) *ovf_cnt = 0;
}

// Blocks [0,256): subgraph cosine blocks -> COMPACT attr values (coalesced)
//                 + inv_map scatter (32 stores per block).
// Blocks [256,1280): raw edges -> per-row bins (4 B stores into ~5 MB, cache-resident).
__global__ __launch_bounds__(256) void build_kernel(
        const float* __restrict__ x,
        const float* __restrict__ Wc,
        const float* __restrict__ sscore,
        const int*   __restrict__ smap,
        const int*   __restrict__ rei,
        int*   __restrict__ counts,
        int*   __restrict__ inv_map,
        float* __restrict__ attr_vals,
        int*   __restrict__ raw_cols,
        int*   __restrict__ ovf_cnt,
        uint2* __restrict__ ovf)
{
    const int tid = threadIdx.x;

    if (blockIdx.x >= N_SUB) {
        int e = (blockIdx.x - N_SUB) * 256 + tid;
        int r = rei[e];
        int c = rei[E_RAW + e];
        int slot = atomicAdd(&counts[r], 1);
        if (slot < CAP_E) {
            raw_cols[(size_t)r * CAP_E + slot] = c;
        } else {
            int o = atomicAdd(ovf_cnt, 1);
            if (o < OVF_CAP) ovf[o] = make_uint2((unsigned)r, (unsigned)c);
        }
        return;
    }

    const int s    = blockIdx.x;
    const int base = s * SUB_SZ;

    __shared__ float xs[SUB_SZ][D + 1];
    __shared__ float w2[N_PERS][D];
    __shared__ float rnorm[N_PERS][SUB_SZ];
    __shared__ float rowscore;

    for (int k = tid; k < SUB_SZ * D; k += 256) {
        int i = k >> 7;
        int d = k & (D - 1);
        xs[i][d] = x[(base + i) * D + d];
    }
    for (int k = tid; k < N_PERS * D; k += 256) {
        float w = Wc[k];
        ((float*)w2)[k] = w * w;
    }
    if (tid < SUB_SZ) inv_map[smap[base + tid]] = base + tid;
    if (tid == 0) {
        int g4 = (s >> 2) << 2;
        float sum = sscore[g4] + sscore[g4 + 1] + sscore[g4 + 2] + sscore[g4 + 3];
        rowscore = (sscore[s] / sum) * LAMB1;
    }
    __syncthreads();

    if (tid < N_PERS * SUB_SZ) {
        int p = tid >> 5;
        int i = tid & 31;
        float acc = 0.f;
        #pragma unroll 8
        for (int d = 0; d < D; ++d) {
            float v = xs[i][d];
            acc = fmaf(v * v, w2[p][d], acc);
        }
        rnorm[p][i] = 1.0f / fmaxf(sqrtf(acc), 1e-12f);
    }
    __syncthreads();

    // write ALL 1024 slots (0 for diag / below-epsilon) -> coalesced 4 KB/block
    for (int e = tid; e < SUB_SZ * SUB_SZ; e += 256) {
        int i = e >> 5;
        int j = e & 31;
        float v = 0.f;
        if (i != j) {
            float a0 = 0.f, a1 = 0.f, a2 = 0.f, a3 = 0.f;
            #pragma unroll 8
            for (int d = 0; d < D; ++d) {
                float prod = xs[i][d] * xs[j][d];
                a0 = fmaf(prod, w2[0][d], a0);
                a1 = fmaf(prod, w2[1][d], a1);
                a2 = fmaf(prod, w2[2][d], a2);
                a3 = fmaf(prod, w2[3][d], a3);
            }
            float adj = 0.25f * (a0 * rnorm[0][i] * rnorm[0][j] +
                                 a1 * rnorm[1][i] * rnorm[1][j] +
                                 a2 * rnorm[2][i] * rnorm[2][j] +
                                 a3 * rnorm[3][i] * rnorm[3][j]);
            if (adj > EPSILON) v = adj * rowscore;
        }
        attr_vals[(size_t)base * SUB_SZ + e] = v;
    }
}

// One block per output row: zero 48 KB LDS row image, patch entries via LDS
// atomics, stream final row with NT float4 stores. Single HBM pass over out.
__global__ __launch_bounds__(256) void rowfill_kernel(
        const int*   __restrict__ counts,
        const int*   __restrict__ inv_map,
        const float* __restrict__ attr_vals,
        const int*   __restrict__ raw_cols,
        const int*   __restrict__ smap,
        float* __restrict__ out)
{
    __shared__ float row[N_FULL];            // 48 KB -> 3 blocks/CU
    const int r   = blockIdx.x;
    const int tid = threadIdx.x;

    f4_t* row4 = (f4_t*)row;
    const f4_t z = (f4_t){0.f, 0.f, 0.f, 0.f};
    #pragma unroll
    for (int k = 0; k < N_FULL / 4 / 256; ++k)     // 12 iters
        row4[tid + k * 256] = z;
    __syncthreads();

    // attr patch: this row's 31 cosine values (if row is a selected node)
    int i = inv_map[r];
    if (i >= 0 && tid < SUB_SZ) {
        float v = attr_vals[(size_t)i * SUB_SZ + tid];
        if (v != 0.f) {
            int c = smap[(i >> 5) * SUB_SZ + tid];
            atomicAdd(&row[c], v);
        }
    }
    // raw-edge patch
    int cnt = counts[r];
    if (cnt > CAP_E) cnt = CAP_E;
    for (int e = tid; e < cnt; e += 256) {
        int c = raw_cols[(size_t)r * CAP_E + e];
        atomicAdd(&row[c], 1.0f - LAMB1);
    }
    __syncthreads();

    f4_t* dst = (f4_t*)(out + (size_t)r * N_FULL);
    #pragma unroll
    for (int k = 0; k < N_FULL / 4 / 256; ++k)
        __builtin_nontemporal_store(row4[tid + k * 256], &dst[tid + k * 256]);
}

// Apply overflow entries (expected count: 0) with global atomics after fill.
__global__ __launch_bounds__(256) void ovf_kernel(const int* __restrict__ ovf_cnt,
                                                  const uint2* __restrict__ ovf,
                                                  float* __restrict__ out)
{
    int n = *ovf_cnt;
    if (n > OVF_CAP) n = OVF_CAP;
    for (int t = blockIdx.x * 256 + threadIdx.x; t < n; t += gridDim.x * 256) {
        uint2 e = ovf[t];
        atomicAdd(&out[(size_t)e.x * N_FULL + e.y], 1.0f - LAMB1);
    }
}

// ---------------- fallback path (R3): zero fill + atomic scatter ----------------
#define N4_TOTAL 37748736
#define FILL_BLOCKS 4096
#define PER_BLOCK (N4_TOTAL / FILL_BLOCKS)
#define FILL_ITERS (PER_BLOCK / 256)

__global__ __launch_bounds__(256) void zero_kernel(f4_t* __restrict__ out)
{
    size_t base = (size_t)blockIdx.x * PER_BLOCK + threadIdx.x;
    const f4_t z = (f4_t){0.f, 0.f, 0.f, 0.f};
    #pragma unroll
    for (int k = 0; k < FILL_ITERS; ++k)
        __builtin_nontemporal_store(z, &out[base + (size_t)k * 256]);
}

__global__ __launch_bounds__(256) void scatter_kernel(
        const float* __restrict__ x,
        const float* __restrict__ Wc,
        const float* __restrict__ sscore,
        const int*   __restrict__ smap,
        const int*   __restrict__ rei,
        float* __restrict__ out)
{
    const int tid = threadIdx.x;

    if (blockIdx.x >= N_SUB) {
        int e = (blockIdx.x - N_SUB) * 256 + tid;
        long long r = rei[e];
        long long c = rei[E_RAW + e];
        atomicAdd(&out[r * (long long)N_FULL + c], 1.0f - LAMB1);
        return;
    }

    const int s    = blockIdx.x;
    const int base = s * SUB_SZ;

    __shared__ float xs[SUB_SZ][D + 1];
    __shared__ float w2[N_PERS][D];
    __shared__ float rnorm[N_PERS][SUB_SZ];
    __shared__ int   map_s[SUB_SZ];
    __shared__ float rowscore;

    for (int k = tid; k < SUB_SZ * D; k += 256) {
        int i = k >> 7;
        int d = k & (D - 1);
        xs[i][d] = x[(base + i) * D + d];
    }
    for (int k = tid; k < N_PERS * D; k += 256) {
        float w = Wc[k];
        ((float*)w2)[k] = w * w;
    }
    if (tid < SUB_SZ) map_s[tid] = smap[base + tid];
    if (tid == 0) {
        int g4 = (s >> 2) << 2;
        float sum = sscore[g4] + sscore[g4 + 1] + sscore[g4 + 2] + sscore[g4 + 3];
        rowscore = (sscore[s] / sum) * LAMB1;
    }
    __syncthreads();

    if (tid < N_PERS * SUB_SZ) {
        int p = tid >> 5;
        int i = tid & 31;
        float acc = 0.f;
        #pragma unroll 8
        for (int d = 0; d < D; ++d) {
            float v = xs[i][d];
            acc = fmaf(v * v, w2[p][d], acc);
        }
        rnorm[p][i] = 1.0f / fmaxf(sqrtf(acc), 1e-12f);
    }
    __syncthreads();

    for (int e = tid; e < SUB_SZ * SUB_SZ; e += 256) {
        int i = e >> 5;
        int j = e & 31;
        if (i == j) continue;
        float a0 = 0.f, a1 = 0.f, a2 = 0.f, a3 = 0.f;
        #pragma unroll 8
        for (int d = 0; d < D; ++d) {
            float prod = xs[i][d] * xs[j][d];
            a0 = fmaf(prod, w2[0][d], a0);
            a1 = fmaf(prod, w2[1][d], a1);
            a2 = fmaf(prod, w2[2][d], a2);
            a3 = fmaf(prod, w2[3][d], a3);
        }
        float adj = 0.25f * (a0 * rnorm[0][i] * rnorm[0][j] +
                             a1 * rnorm[1][i] * rnorm[1][j] +
                             a2 * rnorm[2][i] * rnorm[2][j] +
                             a3 * rnorm[3][i] * rnorm[3][j]);
        if (adj > EPSILON) {
            long long row = map_s[i];
            long long col = map_s[j];
            atomicAdd(&out[row * (long long)N_FULL + col], adj * rowscore);
        }
    }
}

extern "C" void kernel_launch(void* const* d_in, const int* in_sizes, int n_in,
                              void* d_out, int out_size, void* d_ws, size_t ws_size,
                              hipStream_t stream) {
    const float* x      = (const float*)d_in[0];
    const float* Wc     = (const float*)d_in[1];
    const float* sscore = (const float*)d_in[2];
    const int* smap = (const int*)d_in[4];
    const int* rei  = (const int*)d_in[7];
    float* out = (float*)d_out;

    if (ws_size >= WS_NEEDED) {
        char* ws = (char*)d_ws;
        int*   counts    = (int*)(ws + OFF_COUNTS);
        int*   inv_map   = (int*)(ws + OFF_INVMAP);
        float* attr_vals = (float*)(ws + OFF_ATTR);
        int*   raw_cols  = (int*)(ws + OFF_RAWCOLS);
        int*   ovf_cnt   = (int*)(ws + OFF_OVFCNT);
        uint2* ovf       = (uint2*)(ws + OFF_OVF);

        prep_kernel<<<(N_FULL + 255) / 256, 256, 0, stream>>>(counts, inv_map, ovf_cnt);
        build_kernel<<<N_SUB + E_RAW / 256, 256, 0, stream>>>(
            x, Wc, sscore, smap, rei, counts, inv_map, attr_vals, raw_cols, ovf_cnt, ovf);
        rowfill_kernel<<<N_FULL, 256, 0, stream>>>(
            counts, inv_map, attr_vals, raw_cols, smap, out);
        ovf_kernel<<<16, 256, 0, stream>>>(ovf_cnt, ovf, out);
    } else {
        zero_kernel<<<FILL_BLOCKS, 256, 0, stream>>>((f4_t*)out);
        scatter_kernel<<<N_SUB + E_RAW / 256, 256, 0, stream>>>(
            x, Wc, sscore, smap, rei, out);
    }
}